// Round 15
// baseline (170.963 us; speedup 1.0000x reference)
//
#include <hip/hip_runtime.h>
#include <math.h>

// RecurNN: B=256, L=256, E=100, T=255.
// x_t = W1L*left_t + W1R*right_t + b1; h_t = tanh(x_t); out = sigmoid(W2 h_254 + b2).
// These inputs: right_t always a leaf; left_t = node t-1 (leaf only at t=0).
//
// R15 = R14 with ONE change: consumer broadcast mechanism.
//   Consumers (waves 0,1) read h(t-1) via 25 sequential WAVE-UNIFORM
//   ds_read_b128 quads (same-address broadcast, conflict-free, DS pipe) with
//   immediate fma consumption (live quads 1-2 -> no register bulge / spill;
//   R14's 16-live-quad hybrid dropped VGPR to 112 = spill, masking the gain).
//   Zero v_readlane in the consumer (suspected 4-8 cyc/op = the 1400-cyc floor).
//   Producers (waves 2..7, 3 pairs, 3-tick dilation, readlane GALL) unchanged.
//   Sync: one "s_waitcnt lgkmcnt(0); s_barrier" per tick; vmcnt never drained.

#define Bc 256
#define Lc 256
#define Ec 100
#define Tc 255
#define W1cols 200

#define RL(v, k) __int_as_float(__builtin_amdgcn_readlane(__float_as_int(v), (k)))

#define REP100(X) \
 X(0) X(1) X(2) X(3) X(4) X(5) X(6) X(7) X(8) X(9) X(10) X(11) X(12) X(13) X(14) X(15) \
 X(16) X(17) X(18) X(19) X(20) X(21) X(22) X(23) X(24) X(25) X(26) X(27) X(28) X(29) X(30) X(31) \
 X(32) X(33) X(34) X(35) X(36) X(37) X(38) X(39) X(40) X(41) X(42) X(43) X(44) X(45) X(46) X(47) \
 X(48) X(49) X(50) X(51) X(52) X(53) X(54) X(55) X(56) X(57) X(58) X(59) X(60) X(61) X(62) X(63) \
 X(64) X(65) X(66) X(67) X(68) X(69) X(70) X(71) X(72) X(73) X(74) X(75) X(76) X(77) X(78) X(79) \
 X(80) X(81) X(82) X(83) X(84) X(85) X(86) X(87) X(88) X(89) X(90) X(91) X(92) X(93) X(94) X(95) \
 X(96) X(97) X(98) X(99)

#define DECLW(k) float w##k;

// producer selector (k literal; ternaries fold)
#define SRCP(k) RL((k) < 64 ? vA : vB, (k) < 64 ? (k) : (k) - 64)

#define G8(S,a,b,c,d,e,f,g,h2) { \
    const float r0_=S(a), r1_=S(b), r2_=S(c), r3_=S(d), \
                r4_=S(e), r5_=S(f), r6_=S(g), r7_=S(h2); \
    acc0 = fmaf(r0_, w##a, acc0); acc1 = fmaf(r1_, w##b, acc1); \
    acc2 = fmaf(r2_, w##c, acc2); acc3 = fmaf(r3_, w##d, acc3); \
    acc0 = fmaf(r4_, w##e, acc0); acc1 = fmaf(r5_, w##f, acc1); \
    acc2 = fmaf(r6_, w##g, acc2); acc3 = fmaf(r7_, w##h2, acc3); }
#define G4(S,a,b,c,d) { \
    const float r0_=S(a), r1_=S(b), r2_=S(c), r3_=S(d); \
    acc0 = fmaf(r0_, w##a, acc0); acc1 = fmaf(r1_, w##b, acc1); \
    acc2 = fmaf(r2_, w##c, acc2); acc3 = fmaf(r3_, w##d, acc3); }

// producer k-chunks (one per tick)
#define CHUNK0(S) G8(S,0,1,2,3,4,5,6,7) G8(S,8,9,10,11,12,13,14,15) \
                  G8(S,16,17,18,19,20,21,22,23) G8(S,24,25,26,27,28,29,30,31)
#define CHUNK1(S) G8(S,32,33,34,35,36,37,38,39) G8(S,40,41,42,43,44,45,46,47) \
                  G8(S,48,49,50,51,52,53,54,55) G8(S,56,57,58,59,60,61,62,63) \
                  G4(S,64,65,66,67)
#define CHUNK2(S) G8(S,68,69,70,71,72,73,74,75) G8(S,76,77,78,79,80,81,82,83) \
                  G8(S,84,85,86,87,88,89,90,91) G8(S,92,93,94,95,96,97,98,99)

// consumer: one uniform quad -> 4 fmas, quad dies immediately (no pressure)
#define MQ(q,a,b,c,d) { \
    const float4 h4_ = *(const float4*)(hrow + 4*(q)); \
    acc0 = fmaf(h4_.x, w##a, acc0); acc1 = fmaf(h4_.y, w##b, acc1); \
    acc2 = fmaf(h4_.z, w##c, acc2); acc3 = fmaf(h4_.w, w##d, acc3); }

#define MQALL \
    MQ(0,0,1,2,3)      MQ(1,4,5,6,7)      MQ(2,8,9,10,11)    MQ(3,12,13,14,15)  \
    MQ(4,16,17,18,19)  MQ(5,20,21,22,23)  MQ(6,24,25,26,27)  MQ(7,28,29,30,31)  \
    MQ(8,32,33,34,35)  MQ(9,36,37,38,39)  MQ(10,40,41,42,43) MQ(11,44,45,46,47) \
    MQ(12,48,49,50,51) MQ(13,52,53,54,55) MQ(14,56,57,58,59) MQ(15,60,61,62,63) \
    MQ(16,64,65,66,67) MQ(17,68,69,70,71) MQ(18,72,73,74,75) MQ(19,76,77,78,79) \
    MQ(20,80,81,82,83) MQ(21,84,85,86,87) MQ(22,88,89,90,91) MQ(23,92,93,94,95) \
    MQ(24,96,97,98,99)

// generic fallback dot (weights from global; never hot for these inputs)
__device__ __noinline__ float slow_dot(const float* rp, const float* wr) {
    float a0 = 0.f, a1 = 0.f, a2 = 0.f, a3 = 0.f;
    for (int qq = 0; qq < 25; ++qq) {
        float4 h4 = *(const float4*)(rp + 4 * qq);
        float4 w4 = *(const float4*)(wr + 4 * qq);
        a0 = fmaf(w4.x, h4.x, a0); a1 = fmaf(w4.y, h4.y, a1);
        a2 = fmaf(w4.z, h4.z, a2); a3 = fmaf(w4.w, h4.w, a3);
    }
    return (a0 + a1) + (a2 + a3);
}

__global__ __launch_bounds__(512, 2)
void fused(const int* __restrict__ token_ids,
           const int* __restrict__ comp_left,
           const int* __restrict__ comp_right,
           const float* __restrict__ emb,
           const float* __restrict__ W1,
           const float* __restrict__ b1,
           const float* __restrict__ W2,
           const float* __restrict__ b2,
           float* __restrict__ out)
{
    const int b    = blockIdx.x;
    const int tid  = threadIdx.x;          // 0..511
    const int wv   = tid >> 6;             // 0,1 consumers; 2..7 producers
    const int l    = tid & 63;
    const bool cons = (wv < 2);
    const int lc   = (l < 50) ? l : 49;

    __shared__ __align__(16) float hist[Tc * Ec];   // 102000 B (zero = unwritten)
    __shared__ float cring[4][Ec];                  // c ring
    __shared__ int2  ccS[Tc];
    __shared__ int   tokRS[Tc], tokLS[Tc];          // leaf tokens (-1 = internal)
    __shared__ float red[2];

    // ---- prologue staging ----
    for (int i = tid; i < Tc; i += 512) {
        const int cl = comp_left [b * Tc + i];
        const int cr = comp_right[b * Tc + i];
        ccS[i]   = make_int2(cl, cr);
        tokRS[i] = (cr < Lc) ? token_ids[b * Lc + cr] : -1;
        tokLS[i] = (cl < Lc) ? token_ids[b * Lc + cl] : -1;
    }
    {   const float4 z4 = make_float4(0.f, 0.f, 0.f, 0.f);
        for (int i = tid; i < (Tc * Ec) / 4; i += 512) ((float4*)hist)[i] = z4;
    }

    // ---- role weights: consumer W1L row; producer W1R row (pair-half rows) ----
    const int prow = 50 * ((wv - 2) & 1) + lc;            // producer row (waves 2..7)
    const int erow = cons ? (50 * wv + lc) : prow;
    const float* wrow = W1 + (size_t)erow * W1cols + (cons ? 0 : Ec);
    REP100(DECLW)
#define LOADW(k) w##k = wrow[k];
    REP100(LOADW)
#undef LOADW
    const float b1e = b1[erow];
    const float w2e = W2[erow];
    const float b2v = b2[0];

    __syncthreads();   // staging + weights visible

    // ---- persistent state ----
    float vh = 0.f;                        // consumer: own h value (lanes 0-49)
    int2  cc = make_int2(0, 0);
    float pvA = 0.f, pvB = 0.f;            // producer: row being consumed (3-tick window)
    float nA = 0.f, nB = 0.f;              // producer: row in flight
    float acc0 = 0.f, acc1 = 0.f, acc2 = 0.f, acc3 = 0.f;   // producer accs (persist)
    int   tcur = 0, phc = 0;

    if (cons) {
        cc = ccS[0];
    } else {
        // ---- producer prologue: pair p computes c[p] fully; issue loads for p+3 ----
        const int p = (wv - 2) >> 1;
        tcur = p + 3;
        phc  = -p;
        const int tk0 = __builtin_amdgcn_readfirstlane(tokRS[p]);
        float pA = 0.f, pB = 0.f;
        if (tk0 >= 0) {
            const float* g = emb + (size_t)tk0 * Ec;
            pA = g[l];
            if (l < 36) pB = g[64 + l];
        }
        acc0 = b1e;
        { const float vA = pA, vB = pB; CHUNK0(SRCP) CHUNK1(SRCP) CHUNK2(SRCP) }
        if (l < 50) cring[p & 3][erow] = (acc0 + acc1) + (acc2 + acc3);
        const int tk3 = (p + 3 < Tc) ? __builtin_amdgcn_readfirstlane(tokRS[p + 3]) : -1;
        if (tk3 >= 0) {
            const float* g = emb + (size_t)tk3 * Ec;
            nA = g[l];
            nB = (l < 36) ? g[64 + l] : 0.f;
        } else { nA = 0.f; nB = 0.f; }
    }

    // ---- main loop: tick i; consumer does t=i-1; producers build ahead ----
    #pragma unroll 1
    for (int i = 0; i <= Tc; ++i) {
        if (!cons) {
            // ================= PRODUCER (3-tick window per c) =================
            if (phc >= 0 && tcur < Tc) {
                if (phc == 0) {
                    pvA = nA; pvB = nB;            // loads issued 3 ticks ago
                    acc0 = b1e; acc1 = 0.f; acc2 = 0.f; acc3 = 0.f;
                    const int tnx = tcur + 3;      // issue next window's loads
                    const int tk = (tnx < Tc) ? __builtin_amdgcn_readfirstlane(tokRS[tnx]) : -1;
                    if (tk >= 0) {
                        const float* g = emb + (size_t)tk * Ec;
                        nA = g[l];
                        nB = (l < 36) ? g[64 + l] : 0.f;
                    } else { nA = 0.f; nB = 0.f; }
                    { const float vA = pvA, vB = pvB; CHUNK0(SRCP) }
                } else if (phc == 1) {
                    { const float vA = pvA, vB = pvB; CHUNK1(SRCP) }
                } else {
                    { const float vA = pvA, vB = pvB; CHUNK2(SRCP) }
                    if (l < 50) cring[tcur & 3][erow] = (acc0 + acc1) + (acc2 + acc3);
                    tcur += 3;
                }
            }
            phc = (phc >= 2) ? 0 : phc + 1;
        } else {
            // ================= CONSUMER =================
            const int tc = i - 1;
            if (tc >= 0) {
                const int li = __builtin_amdgcn_readfirstlane(cc.x);
                const int ri = __builtin_amdgcn_readfirstlane(cc.y);
                const int2 ccn = (tc + 1 < Tc) ? ccS[tc + 1] : make_int2(0, 0);
                float cv = (l < 50) ? cring[tc & 3][erow] : 0.f;
                acc0 = 0.f; acc1 = 0.f; acc2 = 0.f; acc3 = 0.f;

                if (tc >= 1 && li == Lc + tc - 1) {
                    // fast path: left = previous node. 25 uniform ds_read_b128
                    // broadcasts, each consumed immediately (no register bulge).
                    const float* hrow = &hist[(size_t)(tc - 1) * Ec];
                    MQALL
                } else if (li >= Lc) {
                    acc0 += slow_dot(&hist[(size_t)min(li - Lc, Tc - 1) * Ec],
                                     W1 + (size_t)erow * W1cols);
                } else {
                    const int tl = __builtin_amdgcn_readfirstlane(tokLS[tc]);
                    acc0 += slow_dot(emb + (size_t)max(tl, 0) * Ec,
                                     W1 + (size_t)erow * W1cols);
                }
                if (ri >= Lc)
                    acc0 += slow_dot(&hist[(size_t)min(ri - Lc, Tc - 1) * Ec],
                                     W1 + (size_t)erow * W1cols + Ec);

                const float x = ((acc0 + acc1) + (acc2 + acc3)) + cv;
                const float u = __expf(2.f * x);
                vh = 1.f - 2.f / (u + 1.f);          // tanh, exact identity
                if (l < 50) hist[(size_t)tc * Ec + erow] = vh;
                cc = ccn;
            }
        }
        // one barrier per tick; vmcnt NOT drained (producer loads stay in flight)
        asm volatile("s_waitcnt lgkmcnt(0)\n\ts_barrier" ::: "memory");
    }

    // ---- out[b] = sigmoid(W2 . h_254 + b2) ----
    if (cons) {
        float p = (l < 50) ? w2e * vh : 0.f;
        #pragma unroll
        for (int off = 32; off > 0; off >>= 1) p += __shfl_down(p, off, 64);
        if (l == 0) red[wv] = p;
    }
    __syncthreads();
    if (tid == 0) out[b] = 1.f / (1.f + __expf(-(red[0] + red[1] + b2v)));
}

extern "C" void kernel_launch(void* const* d_in, const int* in_sizes, int n_in,
                              void* d_out, int out_size, void* d_ws, size_t ws_size,
                              hipStream_t stream) {
    const int*   token_ids  = (const int*)  d_in[0];
    const int*   comp_left  = (const int*)  d_in[1];
    const int*   comp_right = (const int*)  d_in[2];
    const float* emb        = (const float*)d_in[3];
    const float* W1         = (const float*)d_in[4];
    const float* b1         = (const float*)d_in[5];
    const float* W2         = (const float*)d_in[6];
    const float* b2         = (const float*)d_in[7];
    float*       out        = (float*)d_out;

    fused<<<Bc, 512, 0, stream>>>(token_ids, comp_left, comp_right,
                                  emb, W1, b1, W2, b2, out);
}

// Round 16
// 154.226 us; speedup vs baseline: 1.1085x; 1.1085x over previous
//
#include <hip/hip_runtime.h>
#include <math.h>

// RecurNN: B=256, L=256, E=100, T=255.
// x_t = W1L*left_t + W1R*right_t + b1; h_t = tanh(x_t); out = sigmoid(W2 h_254 + b2).
// These inputs: right_t always a leaf; left_t = node t-1 (leaf only at t=0).
//
// R16: k-split consumers. 512 thr = 8 waves, one block per batch row.
//  waves 0..3 (consumers): wave q owns k-slice [25q,25q+25). Lane l computes
//    partials for rows (l, l+50) -> 50 weight VGPRs (wA/wB, named scalars).
//    RL source vh: lane j of wave q holds h[25q+j] (its OWN finalize output) ->
//    per step: 25 RL + 50 fma, write 2 partials, barrier, read 4 partials,
//    tanh (25 lanes), write hist (for generic paths only). ~95 instr/wave/step
//    vs 200 in R13 -- and zero LDS on the h-broadcast path.
//  waves 4..7 (producers, 2 pairs): pair p builds c[t], t≡p (mod 2), over
//    2-tick windows (k 0-49 / 50-99); emb loads issued 2 ticks (~1200+cyc)
//    ahead (R13's proven pipeline). c[0],c[1] in prologue.
//  Sync: ONE "s_waitcnt lgkmcnt(0); s_barrier" per tick (partial visibility);
//    ping-pong partial buffers make the WAR hazard barrier-free; vmcnt never
//    drained. Generic-path races checked: n==tc-1 is always the register fast
//    path; n<=tc-2 reads are separated by >=1 barrier.

#define Bc 256
#define Lc 256
#define Ec 100
#define Tc 255
#define W1cols 200

#define RL(v, k) __int_as_float(__builtin_amdgcn_readlane(__float_as_int(v), (k)))
#define RF(x)    __builtin_amdgcn_readfirstlane(x)

// ---------------- consumer: 50 named weight scalars ----------------
#define REP25(X) X(0) X(1) X(2) X(3) X(4) X(5) X(6) X(7) X(8) X(9) X(10) X(11) X(12) \
                 X(13) X(14) X(15) X(16) X(17) X(18) X(19) X(20) X(21) X(22) X(23) X(24)
#define DECLWC(j) float wA##j, wB##j;
#define LOADWC(j) { wA##j = rowA[j]; wB##j = rowB[j]; }
// 2 k's per macro, 4 fma chains
#define CM2(a,b) { const float ra_ = RL(sv,(a)), rb_ = RL(sv,(b)); \
    accA0 = fmaf(ra_, wA##a, accA0); accB0 = fmaf(ra_, wB##a, accB0); \
    accA1 = fmaf(rb_, wA##b, accA1); accB1 = fmaf(rb_, wB##b, accB1); }
#define CM1(a) { const float ra_ = RL(sv,(a)); \
    accA0 = fmaf(ra_, wA##a, accA0); accB0 = fmaf(ra_, wB##a, accB0); }
#define CMALL CM2(0,1) CM2(2,3) CM2(4,5) CM2(6,7) CM2(8,9) CM2(10,11) CM2(12,13) \
              CM2(14,15) CM2(16,17) CM2(18,19) CM2(20,21) CM2(22,23) CM1(24)

// ---------------- producer: 100 named weight scalars ----------------
#define REP100(X) \
 X(0) X(1) X(2) X(3) X(4) X(5) X(6) X(7) X(8) X(9) X(10) X(11) X(12) X(13) X(14) X(15) \
 X(16) X(17) X(18) X(19) X(20) X(21) X(22) X(23) X(24) X(25) X(26) X(27) X(28) X(29) X(30) X(31) \
 X(32) X(33) X(34) X(35) X(36) X(37) X(38) X(39) X(40) X(41) X(42) X(43) X(44) X(45) X(46) X(47) \
 X(48) X(49) X(50) X(51) X(52) X(53) X(54) X(55) X(56) X(57) X(58) X(59) X(60) X(61) X(62) X(63) \
 X(64) X(65) X(66) X(67) X(68) X(69) X(70) X(71) X(72) X(73) X(74) X(75) X(76) X(77) X(78) X(79) \
 X(80) X(81) X(82) X(83) X(84) X(85) X(86) X(87) X(88) X(89) X(90) X(91) X(92) X(93) X(94) X(95) \
 X(96) X(97) X(98) X(99)
#define DECLW(k) float w##k;
#define SRCP(k) RL((k) < 64 ? vA : vB, (k) < 64 ? (k) : (k) - 64)
#define G8(S,a,b,c,d,e,f,g,h2) { \
    const float r0_=S(a), r1_=S(b), r2_=S(c), r3_=S(d), \
                r4_=S(e), r5_=S(f), r6_=S(g), r7_=S(h2); \
    acc0 = fmaf(r0_, w##a, acc0); acc1 = fmaf(r1_, w##b, acc1); \
    acc2 = fmaf(r2_, w##c, acc2); acc3 = fmaf(r3_, w##d, acc3); \
    acc0 = fmaf(r4_, w##e, acc0); acc1 = fmaf(r5_, w##f, acc1); \
    acc2 = fmaf(r6_, w##g, acc2); acc3 = fmaf(r7_, w##h2, acc3); }
#define G2(S,a,b) { const float r0_=S(a), r1_=S(b); \
    acc0 = fmaf(r0_, w##a, acc0); acc1 = fmaf(r1_, w##b, acc1); }
#define CHUNKA(S) G8(S,0,1,2,3,4,5,6,7) G8(S,8,9,10,11,12,13,14,15) \
                  G8(S,16,17,18,19,20,21,22,23) G8(S,24,25,26,27,28,29,30,31) \
                  G8(S,32,33,34,35,36,37,38,39) G8(S,40,41,42,43,44,45,46,47) G2(S,48,49)
#define CHUNKB(S) G8(S,50,51,52,53,54,55,56,57) G8(S,58,59,60,61,62,63,64,65) \
                  G8(S,66,67,68,69,70,71,72,73) G8(S,74,75,76,77,78,79,80,81) \
                  G8(S,82,83,84,85,86,87,88,89) G8(S,90,91,92,93,94,95,96,97) G2(S,98,99)

// generic fallback dot (global weights; never hot for these inputs)
__device__ __noinline__ float slow_dot(const float* rp, const float* wr) {
    float a0 = 0.f, a1 = 0.f, a2 = 0.f, a3 = 0.f;
    for (int qq = 0; qq < 25; ++qq) {
        float4 h4 = *(const float4*)(rp + 4 * qq);
        float4 w4 = *(const float4*)(wr + 4 * qq);
        a0 = fmaf(w4.x, h4.x, a0); a1 = fmaf(w4.y, h4.y, a1);
        a2 = fmaf(w4.z, h4.z, a2); a3 = fmaf(w4.w, h4.w, a3);
    }
    return (a0 + a1) + (a2 + a3);
}

__global__ __launch_bounds__(512, 2)
void fused(const int* __restrict__ token_ids,
           const int* __restrict__ comp_left,
           const int* __restrict__ comp_right,
           const float* __restrict__ emb,
           const float* __restrict__ W1,
           const float* __restrict__ b1,
           const float* __restrict__ W2,
           const float* __restrict__ b2,
           float* __restrict__ out)
{
    const int b    = blockIdx.x;
    const int tid  = threadIdx.x;          // 0..511
    const int wv   = tid >> 6;             // 0..3 consumers; 4..7 producers
    const int l    = tid & 63;
    const bool cons = (wv < 4);
    const int q    = wv & 3;               // consumer k-slice id
    const int lc   = (l < 50) ? l : 49;

    __shared__ float hist[Tc * Ec];        // 102000 B (generic paths only)
    __shared__ float cring[4][Ec];         // 1600 B
    __shared__ float part[2][4][Ec];       // 3200 B ping-pong partials
    __shared__ int2  ccS[Tc];              // 2040 B
    __shared__ int   tokRS[Tc], tokLS[Tc]; // 2040 B
    __shared__ float red[4];

    // ---- staging ----
    for (int i = tid; i < Tc; i += 512) {
        const int cl = comp_left [b * Tc + i];
        const int cr = comp_right[b * Tc + i];
        ccS[i]   = make_int2(cl, cr);
        tokRS[i] = (cr < Lc) ? token_ids[b * Lc + cr] : -1;
        tokLS[i] = (cl < Lc) ? token_ids[b * Lc + cl] : -1;
    }
    // (no hist zero-init needed: n<tc rows are always written; n>=tc -> sv=0)

    // ---- weights ----
    // consumer: rows (lc, lc+50), k-slice [25q, 25q+25)
    const float* rowA = W1 + (size_t)lc * W1cols + 25 * q;
    const float* rowB = W1 + (size_t)(lc + 50) * W1cols + 25 * q;
    REP25(DECLWC)
    // producer: full W1R row prow
    const int pw   = wv - 4;               // 0..3
    const int pp_  = pw >> 1;              // pair id 0,1
    const int pm   = pw & 1;               // member: rows 0-49 / 50-99
    const int prow = 50 * pm + lc;
    const float* wrow = W1 + (size_t)prow * W1cols + Ec;
    REP100(DECLW)
    float b1e = 0.f;
    if (cons) { REP25(LOADWC) }
    else {
#define LOADW(k) w##k = wrow[k];
        REP100(LOADW)
#undef LOADW
        b1e = b1[prow];
    }

    __syncthreads();   // staging + weights visible

    // ---- state ----
    float vh = 0.f;                        // consumer lane j<25: h[25q+j]
    int2  cc = make_int2(0, 0);
    int   pp = 0;                          // partial ping-pong
    float pvA = 0.f, pvB = 0.f;            // producer current-window row
    float nA = 0.f, nB = 0.f;              // producer in-flight row
    float acc0 = 0.f, acc1 = 0.f, acc2 = 0.f, acc3 = 0.f;

#define PISSUE(tnext) { \
    const int tk_ = ((tnext) < Tc) ? RF(tokRS[(tnext)]) : -1;               \
    if (tk_ >= 0) { const float* g_ = emb + (size_t)tk_ * Ec;               \
        nA = g_[l]; nB = (l < 36) ? g_[64 + l] : 0.f; }                     \
    else { nA = 0.f; nB = 0.f; } }

    if (cons) {
        cc = ccS[0];
    } else {
        // producer prologue: compute c[pp_] fully; issue loads for pp_+2
        const int tk = RF(tokRS[pp_]);
        float pA = 0.f, pB = 0.f;
        if (tk >= 0) {
            const float* g = emb + (size_t)tk * Ec;
            pA = g[l];
            if (l < 36) pB = g[64 + l];
        }
        acc0 = b1e;
        { const float vA = pA, vB = pB; CHUNKA(SRCP) CHUNKB(SRCP) }
        if (l < 50) cring[pp_ & 3][prow] = (acc0 + acc1) + (acc2 + acc3);
        PISSUE(pp_ + 2)
    }

    // ---- main loop: tick i; consumer handles tc = i-1 ----
    #pragma unroll 1
    for (int i = 0; i <= Tc; ++i) {
        int tc = -1;
        int ri = 0;
        float cv = 0.f;
        if (cons) {
            // ============ CONSUMER partial-compute ============
            tc = i - 1;
            if (tc >= 0) {
                const int li = RF(cc.x);
                ri = RF(cc.y);
                if (l < 25) cv = cring[tc & 3][25 * q + l];   // used post-barrier
                float sv = 0.f;
                if (tc >= 1 && li == Lc + tc - 1) {
                    sv = vh;                                   // register fast path
                } else if (li >= Lc) {
                    const int n = li - Lc;
                    if (n < tc && l < 25) sv = hist[n * Ec + 25 * q + l];
                } else {
                    const int tl = RF(tokLS[tc]);
                    if (tl >= 0 && l < 25) sv = emb[(size_t)tl * Ec + 25 * q + l];
                }
                float accA0 = 0.f, accA1 = 0.f, accB0 = 0.f, accB1 = 0.f;
                CMALL
                if (l < 50) {
                    part[pp][q][l]      = accA0 + accA1;
                    part[pp][q][l + 50] = accB0 + accB1;
                }
            }
        } else {
            // ============ PRODUCER (2-tick windows) ============
            if ((i & 1) == pp_) {          // window start: t = i+2
                const int t = i + 2;
                if (t < Tc) {
                    pvA = nA; pvB = nB;    // loads issued 2 ticks ago
                    PISSUE(t + 2)
                    acc0 = b1e; acc1 = 0.f; acc2 = 0.f; acc3 = 0.f;
                    { const float vA = pvA, vB = pvB; CHUNKA(SRCP) }
                }
            } else {                        // window finish: t = i+1
                const int t = i + 1;
                if (t >= pp_ + 2 && t < Tc) {
                    { const float vA = pvA, vB = pvB; CHUNKB(SRCP) }
                    if (l < 50) cring[t & 3][prow] = (acc0 + acc1) + (acc2 + acc3);
                }
            }
        }

        // one barrier per tick: partial visibility (+ hist/cring ordering)
        asm volatile("s_waitcnt lgkmcnt(0)\n\ts_barrier" ::: "memory");

        if (cons && tc >= 0) {
            // ============ CONSUMER finalize ============
            if (l < 25) {
                const int r = 25 * q + l;
                float x = ((part[pp][0][r] + part[pp][1][r]) +
                           (part[pp][2][r] + part[pp][3][r])) + cv;
                if (ri >= Lc) {            // generic right-internal (never these inputs)
                    const int n = ri - Lc;
                    if (n < tc) x += slow_dot(&hist[n * Ec],
                                              W1 + (size_t)r * W1cols + Ec);
                }
                const float u = __expf(2.f * x);
                vh = 1.f - 2.f / (u + 1.f);            // tanh, exact identity
                hist[tc * Ec + r] = vh;                // for generic paths
            }
            if (tc + 1 < Tc) cc = ccS[tc + 1];
            pp ^= 1;
        }
    }
#undef PISSUE

    // ---- out[b] = sigmoid(W2 . h_254 + b2) ----
    if (cons) {
        float pv = 0.f;
        if (l < 25) pv = W2[25 * q + l] * vh;
        #pragma unroll
        for (int off = 32; off > 0; off >>= 1) pv += __shfl_down(pv, off, 64);
        if (l == 0) red[q] = pv;
    }
    __syncthreads();
    if (tid == 0)
        out[b] = 1.f / (1.f + __expf(-((red[0] + red[1]) + (red[2] + red[3]) + b2[0])));
}

extern "C" void kernel_launch(void* const* d_in, const int* in_sizes, int n_in,
                              void* d_out, int out_size, void* d_ws, size_t ws_size,
                              hipStream_t stream) {
    const int*   token_ids  = (const int*)  d_in[0];
    const int*   comp_left  = (const int*)  d_in[1];
    const int*   comp_right = (const int*)  d_in[2];
    const float* emb        = (const float*)d_in[3];
    const float* W1         = (const float*)d_in[4];
    const float* b1         = (const float*)d_in[5];
    const float* W2         = (const float*)d_in[6];
    const float* b2         = (const float*)d_in[7];
    float*       out        = (float*)d_out;

    fused<<<Bc, 512, 0, stream>>>(token_ids, comp_left, comp_right,
                                  emb, W1, b1, W2, b2, out);
}

// Round 17
// 140.731 us; speedup vs baseline: 1.2148x; 1.0959x over previous
//
#include <hip/hip_runtime.h>
#include <math.h>

// RecurNN: B=256, L=256, E=100, T=255.
// x_t = W1L*left_t + W1R*right_t + b1; h_t = tanh(x_t); out = sigmoid(W2 h_254 + b2).
// These inputs: right_t always a leaf; left_t = node t-1 (leaf only at t=0).
//
// R17 = R16 (k-split consumers, 154us) + T5 s_setprio + unroll-2:
//  - Consumers raise s_setprio(1) across their critical section (CMALL ->
//    partial write -> barrier -> partial read -> tanh), so the co-resident
//    producer wave's ~300 cyc/tick of RL+fma fills consumer STALLS instead of
//    consumer ISSUE slots (R16 measured: 730 cyc issue/SIMD/tick interleaved
//    into the serial chain). Producers have 2-tick deadline slack + a barrier
//    per tick -> no starvation.
//  - Main loop unrolled x2: partial ping-pong index (pp) is compile-time.
//  - One barrier per tick (moved inside role branches; same count).

#define Bc 256
#define Lc 256
#define Ec 100
#define Tc 255
#define W1cols 200

#define RL(v, k) __int_as_float(__builtin_amdgcn_readlane(__float_as_int(v), (k)))
#define RF(x)    __builtin_amdgcn_readfirstlane(x)

// ---------------- consumer: 50 named weight scalars ----------------
#define REP25(X) X(0) X(1) X(2) X(3) X(4) X(5) X(6) X(7) X(8) X(9) X(10) X(11) X(12) \
                 X(13) X(14) X(15) X(16) X(17) X(18) X(19) X(20) X(21) X(22) X(23) X(24)
#define DECLWC(j) float wA##j, wB##j;
#define LOADWC(j) { wA##j = rowA[j]; wB##j = rowB[j]; }
#define CM2(a,b) { const float ra_ = RL(sv,(a)), rb_ = RL(sv,(b)); \
    accA0 = fmaf(ra_, wA##a, accA0); accB0 = fmaf(ra_, wB##a, accB0); \
    accA1 = fmaf(rb_, wA##b, accA1); accB1 = fmaf(rb_, wB##b, accB1); }
#define CM1(a) { const float ra_ = RL(sv,(a)); \
    accA0 = fmaf(ra_, wA##a, accA0); accB0 = fmaf(ra_, wB##a, accB0); }
#define CMALL CM2(0,1) CM2(2,3) CM2(4,5) CM2(6,7) CM2(8,9) CM2(10,11) CM2(12,13) \
              CM2(14,15) CM2(16,17) CM2(18,19) CM2(20,21) CM2(22,23) CM1(24)

// ---------------- producer: 100 named weight scalars ----------------
#define REP100(X) \
 X(0) X(1) X(2) X(3) X(4) X(5) X(6) X(7) X(8) X(9) X(10) X(11) X(12) X(13) X(14) X(15) \
 X(16) X(17) X(18) X(19) X(20) X(21) X(22) X(23) X(24) X(25) X(26) X(27) X(28) X(29) X(30) X(31) \
 X(32) X(33) X(34) X(35) X(36) X(37) X(38) X(39) X(40) X(41) X(42) X(43) X(44) X(45) X(46) X(47) \
 X(48) X(49) X(50) X(51) X(52) X(53) X(54) X(55) X(56) X(57) X(58) X(59) X(60) X(61) X(62) X(63) \
 X(64) X(65) X(66) X(67) X(68) X(69) X(70) X(71) X(72) X(73) X(74) X(75) X(76) X(77) X(78) X(79) \
 X(80) X(81) X(82) X(83) X(84) X(85) X(86) X(87) X(88) X(89) X(90) X(91) X(92) X(93) X(94) X(95) \
 X(96) X(97) X(98) X(99)
#define DECLW(k) float w##k;
#define SRCP(k) RL((k) < 64 ? vA : vB, (k) < 64 ? (k) : (k) - 64)
#define G8(S,a,b,c,d,e,f,g,h2) { \
    const float r0_=S(a), r1_=S(b), r2_=S(c), r3_=S(d), \
                r4_=S(e), r5_=S(f), r6_=S(g), r7_=S(h2); \
    acc0 = fmaf(r0_, w##a, acc0); acc1 = fmaf(r1_, w##b, acc1); \
    acc2 = fmaf(r2_, w##c, acc2); acc3 = fmaf(r3_, w##d, acc3); \
    acc0 = fmaf(r4_, w##e, acc0); acc1 = fmaf(r5_, w##f, acc1); \
    acc2 = fmaf(r6_, w##g, acc2); acc3 = fmaf(r7_, w##h2, acc3); }
#define G2(S,a,b) { const float r0_=S(a), r1_=S(b); \
    acc0 = fmaf(r0_, w##a, acc0); acc1 = fmaf(r1_, w##b, acc1); }
#define CHUNKA(S) G8(S,0,1,2,3,4,5,6,7) G8(S,8,9,10,11,12,13,14,15) \
                  G8(S,16,17,18,19,20,21,22,23) G8(S,24,25,26,27,28,29,30,31) \
                  G8(S,32,33,34,35,36,37,38,39) G8(S,40,41,42,43,44,45,46,47) G2(S,48,49)
#define CHUNKB(S) G8(S,50,51,52,53,54,55,56,57) G8(S,58,59,60,61,62,63,64,65) \
                  G8(S,66,67,68,69,70,71,72,73) G8(S,74,75,76,77,78,79,80,81) \
                  G8(S,82,83,84,85,86,87,88,89) G8(S,90,91,92,93,94,95,96,97) G2(S,98,99)

// generic fallback dot (global weights; never hot for these inputs)
__device__ __noinline__ float slow_dot(const float* rp, const float* wr) {
    float a0 = 0.f, a1 = 0.f, a2 = 0.f, a3 = 0.f;
    for (int qq = 0; qq < 25; ++qq) {
        float4 h4 = *(const float4*)(rp + 4 * qq);
        float4 w4 = *(const float4*)(wr + 4 * qq);
        a0 = fmaf(w4.x, h4.x, a0); a1 = fmaf(w4.y, h4.y, a1);
        a2 = fmaf(w4.z, h4.z, a2); a3 = fmaf(w4.w, h4.w, a3);
    }
    return (a0 + a1) + (a2 + a3);
}

__global__ __launch_bounds__(512, 2)
void fused(const int* __restrict__ token_ids,
           const int* __restrict__ comp_left,
           const int* __restrict__ comp_right,
           const float* __restrict__ emb,
           const float* __restrict__ W1,
           const float* __restrict__ b1,
           const float* __restrict__ W2,
           const float* __restrict__ b2,
           float* __restrict__ out)
{
    const int b    = blockIdx.x;
    const int tid  = threadIdx.x;          // 0..511
    const int wv   = tid >> 6;             // 0..3 consumers; 4..7 producers
    const int l    = tid & 63;
    const bool cons = (wv < 4);
    const int q    = wv & 3;               // consumer k-slice id
    const int lc   = (l < 50) ? l : 49;

    __shared__ float hist[Tc * Ec];        // generic paths only
    __shared__ float cring[4][Ec];
    __shared__ float part[2][4][Ec];       // ping-pong partials
    __shared__ int2  ccS[Tc];
    __shared__ int   tokRS[Tc], tokLS[Tc];
    __shared__ float red[4];

    // ---- staging ----
    for (int i = tid; i < Tc; i += 512) {
        const int cl = comp_left [b * Tc + i];
        const int cr = comp_right[b * Tc + i];
        ccS[i]   = make_int2(cl, cr);
        tokRS[i] = (cr < Lc) ? token_ids[b * Lc + cr] : -1;
        tokLS[i] = (cl < Lc) ? token_ids[b * Lc + cl] : -1;
    }

    // ---- weights ----
    const float* rowA = W1 + (size_t)lc * W1cols + 25 * q;
    const float* rowB = W1 + (size_t)(lc + 50) * W1cols + 25 * q;
    REP25(DECLWC)
    const int pw   = wv - 4;
    const int pp_  = pw >> 1;              // producer pair id 0,1
    const int pm   = pw & 1;
    const int prow = 50 * pm + lc;
    const float* wrow = W1 + (size_t)prow * W1cols + Ec;
    REP100(DECLW)
    float b1e = 0.f;
    if (cons) { REP25(LOADWC) }
    else {
#define LOADW(k) w##k = wrow[k];
        REP100(LOADW)
#undef LOADW
        b1e = b1[prow];
    }

    __syncthreads();

    // ---- state ----
    float vh = 0.f;
    int2  cc = make_int2(0, 0);
    float pvA = 0.f, pvB = 0.f;
    float nA = 0.f, nB = 0.f;
    float acc0 = 0.f, acc1 = 0.f, acc2 = 0.f, acc3 = 0.f;

#define PISSUE(tnext) { \
    const int tk_ = ((tnext) < Tc) ? RF(tokRS[(tnext)]) : -1;               \
    if (tk_ >= 0) { const float* g_ = emb + (size_t)tk_ * Ec;               \
        nA = g_[l]; nB = (l < 36) ? g_[64 + l] : 0.f; }                     \
    else { nA = 0.f; nB = 0.f; } }

    if (cons) {
        cc = ccS[0];
    } else {
        // producer prologue: compute c[pp_] fully; issue loads for pp_+2
        const int tk = RF(tokRS[pp_]);
        float pA = 0.f, pB = 0.f;
        if (tk >= 0) {
            const float* g = emb + (size_t)tk * Ec;
            pA = g[l];
            if (l < 36) pB = g[64 + l];
        }
        acc0 = b1e;
        { const float vA = pA, vB = pB; CHUNKA(SRCP) CHUNKB(SRCP) }
        if (l < 50) cring[pp_ & 3][prow] = (acc0 + acc1) + (acc2 + acc3);
        PISSUE(pp_ + 2)
    }

#define BARRIER asm volatile("s_waitcnt lgkmcnt(0)\n\ts_barrier" ::: "memory");

// one tick: I = tick index (runtime), PPc = compile-time ping-pong, PAR = I&1
#define TICK(I, PPc, PAR)                                                     \
{                                                                             \
    const int i_ = (I);                                                       \
    if (cons) {                                                               \
        const int tc = i_ - 1;                                                \
        if (tc >= 0) {                                                        \
            __builtin_amdgcn_s_setprio(1);                                    \
            const int li = RF(cc.x);                                          \
            const int ri = RF(cc.y);                                          \
            float cv = 0.f;                                                   \
            if (l < 25) cv = cring[tc & 3][25 * q + l];                       \
            float sv = 0.f;                                                   \
            if (tc >= 1 && li == Lc + tc - 1) {                               \
                sv = vh;                       /* register fast path */       \
            } else if (li >= Lc) {                                            \
                const int n = li - Lc;                                        \
                if (n < tc && l < 25) sv = hist[n * Ec + 25 * q + l];         \
            } else {                                                          \
                const int tl = RF(tokLS[tc]);                                 \
                if (tl >= 0 && l < 25) sv = emb[(size_t)tl * Ec + 25 * q + l];\
            }                                                                 \
            float accA0 = 0.f, accA1 = 0.f, accB0 = 0.f, accB1 = 0.f;         \
            CMALL                                                             \
            if (l < 50) {                                                     \
                part[PPc][q][l]      = accA0 + accA1;                         \
                part[PPc][q][l + 50] = accB0 + accB1;                         \
            }                                                                 \
            BARRIER                                                           \
            if (l < 25) {                                                     \
                const int r = 25 * q + l;                                     \
                float x = ((part[PPc][0][r] + part[PPc][1][r]) +              \
                           (part[PPc][2][r] + part[PPc][3][r])) + cv;         \
                if (ri >= Lc) {                                               \
                    const int n = ri - Lc;                                    \
                    if (n < tc) x += slow_dot(&hist[n * Ec],                  \
                                              W1 + (size_t)r * W1cols + Ec);  \
                }                                                             \
                const float u = __expf(2.f * x);                              \
                vh = 1.f - 2.f / (u + 1.f);    /* tanh, exact identity */     \
                hist[tc * Ec + r] = vh;        /* generic paths only */       \
            }                                                                 \
            __builtin_amdgcn_s_setprio(0);                                    \
            if (tc + 1 < Tc) cc = ccS[tc + 1];                                \
        } else {                                                              \
            BARRIER                                                           \
        }                                                                     \
    } else {                                                                  \
        if (pp_ == (PAR)) {                    /* window start: t = i+2 */    \
            const int t = i_ + 2;                                             \
            if (t < Tc) {                                                     \
                pvA = nA; pvB = nB;            /* loads issued 2 ticks ago */ \
                PISSUE(t + 2)                                                 \
                acc0 = b1e; acc1 = 0.f; acc2 = 0.f; acc3 = 0.f;               \
                { const float vA = pvA, vB = pvB; CHUNKA(SRCP) }              \
            }                                                                 \
        } else {                               /* window finish: t = i+1 */   \
            const int t = i_ + 1;                                             \
            if (t >= pp_ + 2 && t < Tc) {                                     \
                { const float vA = pvA, vB = pvB; CHUNKB(SRCP) }              \
                if (l < 50) cring[t & 3][prow] = (acc0 + acc1) + (acc2 + acc3);\
            }                                                                 \
        }                                                                     \
        BARRIER                                                               \
    }                                                                         \
}

    // ---- main loop: 256 ticks, unroll-2 (pp compile-time) ----
    // tick i>=1 uses pp = (i-1)&1: even ticks -> 1, odd ticks -> 0.
    #pragma unroll 1
    for (int i2 = 0; i2 < 256; i2 += 2) {
        TICK(i2,     1, 0)
        TICK(i2 + 1, 0, 1)
    }
#undef TICK
#undef PISSUE
#undef BARRIER

    // ---- out[b] = sigmoid(W2 . h_254 + b2) ----
    if (cons) {
        float pv = 0.f;
        if (l < 25) pv = W2[25 * q + l] * vh;
        #pragma unroll
        for (int off = 32; off > 0; off >>= 1) pv += __shfl_down(pv, off, 64);
        if (l == 0) red[q] = pv;
    }
    __syncthreads();
    if (tid == 0)
        out[b] = 1.f / (1.f + __expf(-((red[0] + red[1]) + (red[2] + red[3]) + b2[0])));
}

extern "C" void kernel_launch(void* const* d_in, const int* in_sizes, int n_in,
                              void* d_out, int out_size, void* d_ws, size_t ws_size,
                              hipStream_t stream) {
    const int*   token_ids  = (const int*)  d_in[0];
    const int*   comp_left  = (const int*)  d_in[1];
    const int*   comp_right = (const int*)  d_in[2];
    const float* emb        = (const float*)d_in[3];
    const float* W1         = (const float*)d_in[4];
    const float* b1         = (const float*)d_in[5];
    const float* W2         = (const float*)d_in[6];
    const float* b2         = (const float*)d_in[7];
    float*       out        = (float*)d_out;

    fused<<<Bc, 512, 0, stream>>>(token_ids, comp_left, comp_right,
                                  emb, W1, b1, W2, b2, out);
}

// Round 18
// 129.686 us; speedup vs baseline: 1.3183x; 1.0852x over previous
//
#include <hip/hip_runtime.h>
#include <math.h>

// RecurNN: B=256, L=256, E=100, T=255.
// x_t = W1L*left_t + W1R*right_t + b1; h_t = tanh(x_t); out = sigmoid(W2 h_254 + b2).
// These inputs: right_t always a leaf; left_t = node t-1 (leaf only at t=0).
//
// R18 = R17 + symmetric k-split producers:
//  waves 0..3 (consumers): wave q owns k-slice [25q,25q+25), lane l rows (l,l+50).
//    Per tick: 25 RL + 50 fma (CMALL), write 2 partials, barrier, finalize
//    (2x ds_read_b128: cons partials + c partials), tanh. setprio(1) in section.
//  waves 4..7 (producers): wave pj owns k-quarter [25pj,25pj+25) of c[t]=b1+W1R*emb.
//    ALL 4 produce c[i+2] at tick i (25 RL + 50 fma each); emb quarter loads
//    ping-pong 2 ticks ahead. Partials -> cpart[8 slots][100][4] (8 deep: slot
//    reuse write at tick t+6 vs read at t+1 -> race-free).
//  One "lgkmcnt(0); s_barrier" rendezvous per tick; vmcnt never drained.

#define Bc 256
#define Lc 256
#define Ec 100
#define Tc 255
#define W1cols 200

#define RL(v, k) __int_as_float(__builtin_amdgcn_readlane(__float_as_int(v), (k)))
#define RF(x)    __builtin_amdgcn_readfirstlane(x)

// ---- 25 weight pairs (50 named scalars) per wave, both roles ----
#define REP25(X) X(0) X(1) X(2) X(3) X(4) X(5) X(6) X(7) X(8) X(9) X(10) X(11) X(12) \
                 X(13) X(14) X(15) X(16) X(17) X(18) X(19) X(20) X(21) X(22) X(23) X(24)
#define DECLWC(j) float wA##j, wB##j;
#define LOADWC(j) { wA##j = rowA[j]; wB##j = rowB[j]; }
#define CM2(a,b) { const float ra_ = RL(sv,(a)), rb_ = RL(sv,(b)); \
    accA0 = fmaf(ra_, wA##a, accA0); accB0 = fmaf(ra_, wB##a, accB0); \
    accA1 = fmaf(rb_, wA##b, accA1); accB1 = fmaf(rb_, wB##b, accB1); }
#define CM1(a) { const float ra_ = RL(sv,(a)); \
    accA0 = fmaf(ra_, wA##a, accA0); accB0 = fmaf(ra_, wB##a, accB0); }
#define CMALL CM2(0,1) CM2(2,3) CM2(4,5) CM2(6,7) CM2(8,9) CM2(10,11) CM2(12,13) \
              CM2(14,15) CM2(16,17) CM2(18,19) CM2(20,21) CM2(22,23) CM1(24)

// generic fallback dot (global weights; never hot for these inputs)
__device__ __noinline__ float slow_dot(const float* rp, const float* wr) {
    float a0 = 0.f, a1 = 0.f, a2 = 0.f, a3 = 0.f;
    for (int qq = 0; qq < 25; ++qq) {
        float4 h4 = *(const float4*)(rp + 4 * qq);
        float4 w4 = *(const float4*)(wr + 4 * qq);
        a0 = fmaf(w4.x, h4.x, a0); a1 = fmaf(w4.y, h4.y, a1);
        a2 = fmaf(w4.z, h4.z, a2); a3 = fmaf(w4.w, h4.w, a3);
    }
    return (a0 + a1) + (a2 + a3);
}

__global__ __launch_bounds__(512, 2)
void fused(const int* __restrict__ token_ids,
           const int* __restrict__ comp_left,
           const int* __restrict__ comp_right,
           const float* __restrict__ emb,
           const float* __restrict__ W1,
           const float* __restrict__ b1,
           const float* __restrict__ W2,
           const float* __restrict__ b2,
           float* __restrict__ out)
{
    const int b    = blockIdx.x;
    const int tid  = threadIdx.x;          // 0..511
    const int wv   = tid >> 6;             // 0..3 consumers; 4..7 producers
    const int l    = tid & 63;
    const bool cons = (wv < 4);
    const int q    = wv & 3;               // consumer k-slice / producer k-quarter
    const int lc   = (l < 50) ? l : 49;

    __shared__ float hist[Tc * Ec];                    // generic paths only
    __shared__ __align__(16) float part[2][Ec][4];     // cons partials (ping-pong)
    __shared__ __align__(16) float cpart[8][Ec][4];    // c partials (8-deep)
    __shared__ int2  ccS[Tc];
    __shared__ int   tokRS[Tc], tokLS[Tc];
    __shared__ float red[4];

    // ---- staging ----
    for (int i = tid; i < Tc; i += 512) {
        const int cl = comp_left [b * Tc + i];
        const int cr = comp_right[b * Tc + i];
        ccS[i]   = make_int2(cl, cr);
        tokRS[i] = (cr < Lc) ? token_ids[b * Lc + cr] : -1;
        tokLS[i] = (cl < Lc) ? token_ids[b * Lc + cl] : -1;
    }

    // ---- weights: 25 pairs per wave (cons = W1L k-slice; prod = W1R k-quarter) ----
    const int kofs = (cons ? 0 : Ec) + 25 * q;
    const float* rowA = W1 + (size_t)lc * W1cols + kofs;
    const float* rowB = W1 + (size_t)(lc + 50) * W1cols + kofs;
    REP25(DECLWC)
    REP25(LOADWC)
    // producer wave 4 (q==0) carries b1
    const float b1eA = (!cons && q == 0) ? b1[lc] : 0.f;
    const float b1eB = (!cons && q == 0) ? b1[lc + 50] : 0.f;

    __syncthreads();

    // ---- state ----
    float vh = 0.f;                        // consumer lane j<25: h[25q+j]
    int2  cc = make_int2(0, 0);
    float vA0 = 0.f, vA1 = 0.f;            // producer emb-quarter ping-pong
    int   tk0 = -1, tk1 = -1;

    if (cons) {
        cc = ccS[0];
    } else {
        // ---- producer prologue: c[0], c[1] directly; issue slots for t=2,3 ----
        for (int t = 0; t < 2; ++t) {
            const int tk = RF(tokRS[t]);
            float sv = 0.f;
            if (tk >= 0 && l < 25) sv = emb[(size_t)tk * Ec + 25 * q + l];
            float accA0 = b1eA, accA1 = 0.f, accB0 = b1eB, accB1 = 0.f;
            if (tk >= 0) { CMALL }
            if (l < 50) {
                cpart[t][lc][q]      = accA0 + accA1;
                cpart[t][lc + 50][q] = accB0 + accB1;
            }
        }
        tk0 = (2 < Tc) ? RF(tokRS[2]) : -1;
        if (tk0 >= 0 && l < 25) vA0 = emb[(size_t)tk0 * Ec + 25 * q + l];
        tk1 = (3 < Tc) ? RF(tokRS[3]) : -1;
        if (tk1 >= 0 && l < 25) vA1 = emb[(size_t)tk1 * Ec + 25 * q + l];
    }

#define BARRIER asm volatile("s_waitcnt lgkmcnt(0)\n\ts_barrier" ::: "memory");

// one tick: I runtime index, PPc compile-time cons ping-pong, PAR = I&1
#define TICK(I, PPc, PAR)                                                     \
{                                                                             \
    const int i_ = (I);                                                       \
    if (cons) {                                                               \
        const int tc = i_ - 1;                                                \
        if (tc >= 0) {                                                        \
            __builtin_amdgcn_s_setprio(1);                                    \
            const int li = RF(cc.x);                                          \
            const int ri = RF(cc.y);                                          \
            float sv = 0.f;                                                   \
            if (tc >= 1 && li == Lc + tc - 1) {                               \
                sv = vh;                       /* register fast path */       \
            } else if (li >= Lc) {                                            \
                const int n = li - Lc;                                        \
                if (n < tc && l < 25) sv = hist[n * Ec + 25 * q + l];         \
            } else {                                                          \
                const int tl = RF(tokLS[tc]);                                 \
                if (tl >= 0 && l < 25) sv = emb[(size_t)tl * Ec + 25 * q + l];\
            }                                                                 \
            float accA0 = 0.f, accA1 = 0.f, accB0 = 0.f, accB1 = 0.f;         \
            CMALL                                                             \
            if (l < 50) {                                                     \
                part[PPc][lc][q]      = accA0 + accA1;                        \
                part[PPc][lc + 50][q] = accB0 + accB1;                        \
            }                                                                 \
            BARRIER                                                           \
            if (l < 25) {                                                     \
                const int r = 25 * q + l;                                     \
                const float4 p4 = *(const float4*)&part[PPc][r][0];           \
                const float4 c4 = *(const float4*)&cpart[tc & 7][r][0];       \
                float x = ((p4.x + p4.y) + (p4.z + p4.w)) +                   \
                          ((c4.x + c4.y) + (c4.z + c4.w));                    \
                if (ri >= Lc) {                                               \
                    const int n = ri - Lc;                                    \
                    if (n < tc) x += slow_dot(&hist[n * Ec],                  \
                                              W1 + (size_t)r * W1cols + Ec);  \
                }                                                             \
                const float u = __expf(2.f * x);                              \
                vh = 1.f - 2.f / (u + 1.f);    /* tanh, exact identity */     \
                hist[tc * Ec + r] = vh;        /* generic paths only */       \
            }                                                                 \
            __builtin_amdgcn_s_setprio(0);                                    \
            if (tc + 1 < Tc) cc = ccS[tc + 1];                                \
        } else {                                                              \
            BARRIER                                                           \
        }                                                                     \
    } else {                                                                  \
        const int t = i_ + 2;                                                 \
        if (t < Tc) {                                                         \
            const float sv  = (PAR) ? vA1 : vA0;   /* loaded 2 ticks ago */   \
            const int   tkc = (PAR) ? tk1 : tk0;                              \
            const int   tn  = t + 2;               /* refill this slot */     \
            const int tknew = (tn < Tc) ? RF(tokRS[tn]) : -1;                 \
            float nv = 0.f;                                                   \
            if (tknew >= 0 && l < 25) nv = emb[(size_t)tknew * Ec + 25 * q + l];\
            if (PAR) { vA1 = nv; tk1 = tknew; } else { vA0 = nv; tk0 = tknew; }\
            float accA0 = b1eA, accA1 = 0.f, accB0 = b1eB, accB1 = 0.f;       \
            if (tkc >= 0) { CMALL }                                           \
            if (l < 50) {                                                     \
                cpart[t & 7][lc][q]      = accA0 + accA1;                     \
                cpart[t & 7][lc + 50][q] = accB0 + accB1;                     \
            }                                                                 \
        }                                                                     \
        BARRIER                                                               \
    }                                                                         \
}

    // ---- main loop: 256 ticks, unroll-2 ----
    #pragma unroll 1
    for (int i2 = 0; i2 < 256; i2 += 2) {
        TICK(i2,     1, 0)
        TICK(i2 + 1, 0, 1)
    }
#undef TICK
#undef BARRIER

    // ---- out[b] = sigmoid(W2 . h_254 + b2) ----
    if (cons) {
        float pv = 0.f;
        if (l < 25) pv = W2[25 * q + l] * vh;
        #pragma unroll
        for (int off = 32; off > 0; off >>= 1) pv += __shfl_down(pv, off, 64);
        if (l == 0) red[q] = pv;
    }
    __syncthreads();
    if (tid == 0)
        out[b] = 1.f / (1.f + __expf(-((red[0] + red[1]) + (red[2] + red[3]) + b2[0])));
}

extern "C" void kernel_launch(void* const* d_in, const int* in_sizes, int n_in,
                              void* d_out, int out_size, void* d_ws, size_t ws_size,
                              hipStream_t stream) {
    const int*   token_ids  = (const int*)  d_in[0];
    const int*   comp_left  = (const int*)  d_in[1];
    const int*   comp_right = (const int*)  d_in[2];
    const float* emb        = (const float*)d_in[3];
    const float* W1         = (const float*)d_in[4];
    const float* b1         = (const float*)d_in[5];
    const float* W2         = (const float*)d_in[6];
    const float* b2         = (const float*)d_in[7];
    float*       out        = (float*)d_out;

    fused<<<Bc, 512, 0, stream>>>(token_ids, comp_left, comp_right,
                                  emb, W1, b1, W2, b2, out);
}